// Round 9
// baseline (237.190 us; speedup 1.0000x reference)
//
#include <hip/hip_runtime.h>
#include <hip/hip_bf16.h>

#define NPTS 4096
#define BATCH 4
#define KNN 20

typedef __attribute__((ext_vector_type(8))) short bf16x8;
typedef __attribute__((ext_vector_type(4))) float f32x4;
typedef __attribute__((ext_vector_type(4))) int i32x4;
typedef unsigned long long u64;

// ws layout (bytes):
//   0      : fp32 tables: w0s[384] b0[64] s1[64] b1[64] wouts[192] bout[3]
//   4096   : whi frags ushort[24576]  (B-fragment layout, hi split)
//   53248  : wlo frags ushort[24576]  (lo split)
//   757760 : xq float4[16384] = (x0,x1,x2,||x||^2)
#define OFF_W0S   0
#define OFF_B0F   384
#define OFF_S1F   448
#define OFF_B1F   512
#define OFF_WOUTS 576
#define OFF_BOUTF 768
#define OFF_WHI_BYTES 4096
#define OFF_WLO_BYTES 53248
#define OFF_XQ_BYTES  757760

__device__ __forceinline__ u64 shflx64(u64 v, int off) {
  int lo = __shfl_xor((int)(v & 0xFFFFFFFFull), off);
  int hi = __shfl_xor((int)(v >> 32), off);
  return ((u64)(unsigned)hi << 32) | (unsigned)lo;
}
__device__ __forceinline__ u64 shflbc64(u64 v, int src) {
  int lo = __shfl((int)(v & 0xFFFFFFFFull), src);
  int hi = __shfl((int)(v >> 32), src);
  return ((u64)(unsigned)hi << 32) | (unsigned)lo;
}

__global__ __launch_bounds__(256) void prep_kernel(
    const float* __restrict__ x,
    const float* __restrict__ w0, const float* __restrict__ g0, const float* __restrict__ b0,
    const float* __restrict__ w1, const float* __restrict__ g1, const float* __restrict__ b1,
    const float* __restrict__ wout, const float* __restrict__ gout, const float* __restrict__ bout,
    float* __restrict__ wsf, unsigned short* __restrict__ whi, unsigned short* __restrict__ wlo,
    float4* __restrict__ xq) {
  const float rs = 1.0f / sqrtf(1.0f + 1e-5f);
  int t = blockIdx.x * 256 + threadIdx.x;
  if (t < 384) wsf[OFF_W0S + t] = w0[t] * (g0[t / 6] * rs);
  if (t < 64) {
    wsf[OFF_B0F + t] = b0[t];
    wsf[OFF_S1F + t] = g1[t] * rs;
    wsf[OFF_B1F + t] = b1[t];
  }
  if (t < 192) wsf[OFF_WOUTS + t] = wout[t] * (gout[t / 64] * rs);
  if (t < 3) wsf[OFF_BOUTF + t] = bout[t];
  if (t < BATCH * NPTS) {
    int bb = t >> 12, j = t & (NPTS - 1);
    const float* xb = x + bb * 3 * NPTS;
    float x0 = xb[j], x1 = xb[NPTS + j], x2 = xb[2 * NPTS + j];
    float xx = x0 * x0 + x1 * x1 + x2 * x2;
    xq[t] = make_float4(x0, x1, x2, xx);
  }
  // B-fragment layout for mfma_f32_16x16x32_bf16: frag ft = kk*4+nt; lane L holds
  // B[k = kk*32 + (L>>4)*8 + j][n = nt*16 + (L&15)], j packed consecutively.
  if (t < 24576) {
    int j = t & 7, L = (t >> 3) & 63, ft = t >> 9;
    int kk = ft >> 2, nt = ft & 3;
    int k = kk * 32 + ((L >> 4) << 3) + j;
    int c = k >> 6, d = k & 63;
    int o = nt * 16 + (L & 15);
    float w = w1[(o * 6 + c) * 64 + d];
    unsigned bw = __float_as_uint(w);
    unsigned hb = bw & 0xFFFF0000u;
    float r = w - __uint_as_float(hb);
    whi[t] = (unsigned short)(bw >> 16);
    wlo[t] = (unsigned short)(__float_as_uint(r) >> 16);
  }
}

// Fused kernel: 4 waves/block = 4 points. Phase 1: per-wave kNN (round-6 v2
// logic verbatim: direct L2 loads, u64 top-2 cache + butterfly argmax), idx ->
// LDS (no global idxbuf). Phase 2: mlp; M-tiles split across waves (wave w ->
// tile w, wave0 also tile 4), so per-wave acc is 16-32 VGPRs (not 80). VALU-heavy
// knn waves and MFMA-heavy mlp waves co-schedule across blocks (m114).
__global__ __launch_bounds__(256) void fused_kernel(const float4* __restrict__ xq,
                                                    const float* __restrict__ wsf,
                                                    const unsigned short* __restrict__ whi,
                                                    const unsigned short* __restrict__ wlo,
                                                    float* __restrict__ out) {
  __shared__ float w0l[448];          // w0s[384] + b0[64]
  __shared__ float v6l[80 * 12];
  __shared__ float pmax[20 * 66];
  __shared__ unsigned short idxl[80];

  const int tid = threadIdx.x;
  const int wv = tid >> 6;
  const int lane = tid & 63;
  const int quad = lane >> 4, l15 = lane & 15;
  const int pt_base = blockIdx.x * 4;
  const int pt = pt_base + wv;          // this wave's point
  const int b = pt >> 12, n = pt & (NPTS - 1);
  const float4* xqb = xq + b * NPTS;

  for (int i = tid; i < 448; i += 256) w0l[i] = wsf[i];

  // ---------------- kNN phase (per wave) ----------------
  const float4 xin = xqb[n];
  const float xi0 = xin.x, xi1 = xin.y, xi2 = xin.z;
  const float nxxi = -xin.w;

  u64 k1 = 0, k2 = 0;
  unsigned lo = 4095u - (unsigned)lane;
#pragma unroll 4
  for (int s = 0; s < 64; ++s) {
    float4 q = xqb[s * 64 + lane];
    float dot = xi0 * q.x + xi1 * q.y + xi2 * q.z;
    float pd = fmaf(2.0f, dot, nxxi) - q.w;   // bit-identical to ref expr
    u64 k = ((u64)(~__float_as_uint(pd)) << 32) | lo;
    lo -= 64u;
    bool c1 = k > k1;
    bool c2 = k > k2;
    u64 tt = c1 ? k1 : k;
    k2 = c2 ? tt : k2;
    k1 = c1 ? k : k1;
  }

  u64 tk = 0;
  unsigned myout = 0;
#pragma unroll 1
  for (int r = 0; r < KNN; ++r) {
    u64 bk = k1;
    for (int off = 32; off > 0; off >>= 1) {
      u64 ok = shflx64(bk, off);
      if (ok > bk) bk = ok;
    }
    unsigned bj = 4095u - (unsigned)(bk & 4095u);
    if (lane == r) myout = bj;
    bool owner = (k1 == bk);
    u64 bit = 1ull << (bj >> 6);
    if (owner) {
      tk |= bit;
      k1 = k2;
      k2 = 0;
    }
    bool need = owner && (k1 == 0);
    u64 nm = __ballot(need);
    if (nm) {
      int LN = __ffsll(nm) - 1;
      int j2 = lane * 64 + LN;
      float4 q = xqb[j2];
      float dot = xi0 * q.x + xi1 * q.y + xi2 * q.z;
      float pd = fmaf(2.0f, dot, nxxi) - q.w;
      u64 kk = ((u64)(~__float_as_uint(pd)) << 32) | (4095u - (unsigned)j2);
      u64 tkl = shflbc64(tk, LN);
      if ((tkl >> lane) & 1) kk = 0;
      u64 w1k = kk;
      for (int off = 32; off > 0; off >>= 1) {
        u64 ok = shflx64(w1k, off);
        if (ok > w1k) w1k = ok;
      }
      u64 kk2 = (kk == w1k) ? 0 : kk;
      u64 w2k = kk2;
      for (int off = 32; off > 0; off >>= 1) {
        u64 ok = shflx64(w2k, off);
        if (ok > w2k) w2k = ok;
      }
      if (lane == LN) { k1 = w1k; k2 = w2k; }
    }
  }
  if (lane < KNN) idxl[wv * KNN + lane] = (unsigned short)myout;

  // preload first B frags (kk=0) — latency hidden under barrier + gather
  const i32x4* whp = (const i32x4*)whi;
  const i32x4* wlp = (const i32x4*)wlo;
  i32x4 wh[4], wl[4];
#pragma unroll
  for (int nt = 0; nt < 4; ++nt) {
    wh[nt] = whp[nt * 64 + lane];
    wl[nt] = wlp[nt * 64 + lane];
  }

  __syncthreads();      // idxl ready

  // ---------------- v6 gather (threads 0..79, one edge each) ----------------
  if (tid < 80) {
    int p = tid / 20;
    int ptg = pt_base + p;
    int bb = ptg >> 12, nn = ptg & (NPTS - 1);
    float4 xi = xq[bb * NPTS + nn];
    int jn = idxl[tid];
    float4 xj = xq[bb * NPTS + jn];
    v6l[tid * 12 + 0] = xj.x - xi.x;
    v6l[tid * 12 + 1] = xj.y - xi.y;
    v6l[tid * 12 + 2] = xj.z - xi.z;
    v6l[tid * 12 + 3] = xi.x;
    v6l[tid * 12 + 4] = xi.y;
    v6l[tid * 12 + 5] = xi.z;
  }
  __syncthreads();      // v6l + w0l ready

  // ---------------- mlp phase: wave wv -> tile wv (+ tile 4 for wave 0) ----------------
  float s1v[4], b1v[4];
#pragma unroll
  for (int nt = 0; nt < 4; ++nt) {
    s1v[nt] = wsf[OFF_S1F + nt * 16 + l15];
    b1v[nt] = wsf[OFF_B1F + nt * 16 + l15];
  }

  const int ntile = (wv == 0) ? 2 : 1;
#pragma unroll 1
  for (int rep = 0; rep < ntile; ++rep) {
    const int t = (rep == 0) ? wv : 4;
    const int row = t * 16 + l15;
    const float* vr = v6l + row * 12;
    float v60 = vr[0], v61 = vr[1], v62 = vr[2];
    float v63 = vr[3], v64 = vr[4], v65 = vr[5];

    if (rep == 1) {     // wave0's second tile: restart B stream at kk=0
#pragma unroll
      for (int nt = 0; nt < 4; ++nt) {
        wh[nt] = whp[nt * 64 + lane];
        wl[nt] = wlp[nt * 64 + lane];
      }
    }

    f32x4 acc[4];
#pragma unroll
    for (int nt = 0; nt < 4; ++nt) acc[nt] = (f32x4){0.f, 0.f, 0.f, 0.f};

#pragma unroll 1
    for (int hh = 0; hh < 2; ++hh) {
      float hf[8];
#pragma unroll
      for (int j = 0; j < 8; ++j) {
        const int d = hh * 32 + quad * 8 + j;
        const float* wr = w0l + d * 6;
        float a = w0l[384 + d] + wr[0] * v60 + wr[1] * v61 + wr[2] * v62
                               + wr[3] * v63 + wr[4] * v64 + wr[5] * v65;
        hf[j] = fmaxf(a, 0.2f * a);
      }

#pragma unroll 1
      for (int cc = 0; cc < 6; ++cc) {
        const int kk = cc * 2 + hh;
        const bool hasnext = !(hh == 1 && cc == 5);
        const int kkn = (cc < 5) ? kk + 2 : 1;
        i32x4 whn[4], wln[4];
        if (hasnext) {
#pragma unroll
          for (int nt = 0; nt < 4; ++nt) {
            whn[nt] = whp[(kkn * 4 + nt) * 64 + lane];
            wln[nt] = wlp[(kkn * 4 + nt) * 64 + lane];
          }
        }
        float vc = v6l[row * 12 + cc];
        float u0 = vc * hf[0], u1 = vc * hf[1], u2 = vc * hf[2], u3 = vc * hf[3];
        float u4 = vc * hf[4], u5 = vc * hf[5], u6 = vc * hf[6], u7 = vc * hf[7];
        unsigned ub0 = __float_as_uint(u0), ub1 = __float_as_uint(u1);
        unsigned ub2 = __float_as_uint(u2), ub3 = __float_as_uint(u3);
        unsigned ub4 = __float_as_uint(u4), ub5 = __float_as_uint(u5);
        unsigned ub6 = __float_as_uint(u6), ub7 = __float_as_uint(u7);
        float r0 = u0 - __uint_as_float(ub0 & 0xFFFF0000u);
        float r1 = u1 - __uint_as_float(ub1 & 0xFFFF0000u);
        float r2 = u2 - __uint_as_float(ub2 & 0xFFFF0000u);
        float r3 = u3 - __uint_as_float(ub3 & 0xFFFF0000u);
        float r4 = u4 - __uint_as_float(ub4 & 0xFFFF0000u);
        float r5 = u5 - __uint_as_float(ub5 & 0xFFFF0000u);
        float r6 = u6 - __uint_as_float(ub6 & 0xFFFF0000u);
        float r7 = u7 - __uint_as_float(ub7 & 0xFFFF0000u);
        i32x4 ah, al;
        ah.x = __builtin_amdgcn_perm(ub1, ub0, 0x07060302);
        ah.y = __builtin_amdgcn_perm(ub3, ub2, 0x07060302);
        ah.z = __builtin_amdgcn_perm(ub5, ub4, 0x07060302);
        ah.w = __builtin_amdgcn_perm(ub7, ub6, 0x07060302);
        al.x = __builtin_amdgcn_perm(__float_as_uint(r1), __float_as_uint(r0), 0x07060302);
        al.y = __builtin_amdgcn_perm(__float_as_uint(r3), __float_as_uint(r2), 0x07060302);
        al.z = __builtin_amdgcn_perm(__float_as_uint(r5), __float_as_uint(r4), 0x07060302);
        al.w = __builtin_amdgcn_perm(__float_as_uint(r7), __float_as_uint(r6), 0x07060302);
        bf16x8 ahv = __builtin_bit_cast(bf16x8, ah);
        bf16x8 alv = __builtin_bit_cast(bf16x8, al);
#pragma unroll
        for (int nt = 0; nt < 4; ++nt) {
          bf16x8 bh = __builtin_bit_cast(bf16x8, wh[nt]);
          bf16x8 bl = __builtin_bit_cast(bf16x8, wl[nt]);
          acc[nt] = __builtin_amdgcn_mfma_f32_16x16x32_bf16(ahv, bh, acc[nt], 0, 0, 0);
          acc[nt] = __builtin_amdgcn_mfma_f32_16x16x32_bf16(ahv, bl, acc[nt], 0, 0, 0);
          acc[nt] = __builtin_amdgcn_mfma_f32_16x16x32_bf16(alv, bh, acc[nt], 0, 0, 0);
        }
        if (hasnext) {
#pragma unroll
          for (int nt = 0; nt < 4; ++nt) { wh[nt] = whn[nt]; wl[nt] = wln[nt]; }
        }
      }
    }

    // per-tile epilogue: BN + lrelu + quad-local max (4 edges, one point)
#pragma unroll
    for (int nt = 0; nt < 4; ++nt) {
      f32x4 a = acc[nt];
      float z0 = a.x * s1v[nt] + b1v[nt]; z0 = fmaxf(z0, 0.2f * z0);
      float z1 = a.y * s1v[nt] + b1v[nt]; z1 = fmaxf(z1, 0.2f * z1);
      float z2 = a.z * s1v[nt] + b1v[nt]; z2 = fmaxf(z2, 0.2f * z2);
      float z3 = a.w * s1v[nt] + b1v[nt]; z3 = fmaxf(z3, 0.2f * z3);
      float m4 = fmaxf(fmaxf(z0, z1), fmaxf(z2, z3));
      pmax[(t * 4 + quad) * 66 + nt * 16 + l15] = m4;
    }
  }
  __syncthreads();      // pmax ready

  // ---------------- final: wave wv finishes point wv ----------------
  {
    float x1 = pmax[(wv * 5 + 0) * 66 + lane];
    x1 = fmaxf(x1, pmax[(wv * 5 + 1) * 66 + lane]);
    x1 = fmaxf(x1, pmax[(wv * 5 + 2) * 66 + lane]);
    x1 = fmaxf(x1, pmax[(wv * 5 + 3) * 66 + lane]);
    x1 = fmaxf(x1, pmax[(wv * 5 + 4) * 66 + lane]);
#pragma unroll
    for (int m = 0; m < 3; ++m) {
      float part = wsf[OFF_WOUTS + m * 64 + lane] * x1;
      for (int off = 32; off > 0; off >>= 1) part += __shfl_xor(part, off);
      if (lane == 0) {
        float ov = part + wsf[OFF_BOUTF + m];
        out[(b * 3 + m) * NPTS + n] = fmaxf(ov, 0.2f * ov);
      }
    }
  }
}

extern "C" void kernel_launch(void* const* d_in, const int* in_sizes, int n_in,
                              void* d_out, int out_size, void* d_ws, size_t ws_size,
                              hipStream_t stream) {
  const float* x    = (const float*)d_in[0];
  const float* w0   = (const float*)d_in[1];
  const float* g0   = (const float*)d_in[2];
  const float* b0   = (const float*)d_in[3];
  const float* w1   = (const float*)d_in[4];
  const float* g1   = (const float*)d_in[5];
  const float* b1   = (const float*)d_in[6];
  const float* wout = (const float*)d_in[7];
  const float* gout = (const float*)d_in[8];
  const float* bout = (const float*)d_in[9];
  float* wsf = (float*)d_ws;
  unsigned short* whi = (unsigned short*)((char*)d_ws + OFF_WHI_BYTES);
  unsigned short* wlo = (unsigned short*)((char*)d_ws + OFF_WLO_BYTES);
  float4* xq = (float4*)((char*)d_ws + OFF_XQ_BYTES);
  float* out = (float*)d_out;

  prep_kernel<<<96, 256, 0, stream>>>(x, w0, g0, b0, w1, g1, b1, wout, gout, bout,
                                      wsf, whi, wlo, xq);
  fused_kernel<<<BATCH * NPTS / 4, 256, 0, stream>>>(xq, wsf, whi, wlo, out);
}

// Round 10
// 184.853 us; speedup vs baseline: 1.2831x; 1.2831x over previous
//
#include <hip/hip_runtime.h>
#include <hip/hip_bf16.h>

#define NPTS 4096
#define BATCH 4
#define KNN 20

typedef __attribute__((ext_vector_type(8))) short bf16x8;
typedef __attribute__((ext_vector_type(4))) float f32x4;
typedef __attribute__((ext_vector_type(4))) int i32x4;
typedef unsigned long long u64;

// ws layout (bytes):
//   0      : fp32 tables: w0s[384] b0[64] s1[64] b1[64] wouts[192] bout[3]
//   4096   : whi frags ushort[24576]  (B-fragment layout, hi split)
//   53248  : wlo frags ushort[24576]  (lo split)
//   102400 : idxbuf ushort[16384*20]  (655360 B)
//   757760 : xq float4[16384] = (x0,x1,x2,||x||^2)
#define OFF_W0S   0
#define OFF_B0F   384
#define OFF_S1F   448
#define OFF_B1F   512
#define OFF_WOUTS 576
#define OFF_BOUTF 768
#define OFF_WHI_BYTES 4096
#define OFF_WLO_BYTES 53248
#define OFF_IDX_BYTES 102400
#define OFF_XQ_BYTES  757760

__device__ __forceinline__ u64 shflx64(u64 v, int off) {
  int lo = __shfl_xor((int)(v & 0xFFFFFFFFull), off);
  int hi = __shfl_xor((int)(v >> 32), off);
  return ((u64)(unsigned)hi << 32) | (unsigned)lo;
}
__device__ __forceinline__ u64 shflbc64(u64 v, int src) {
  int lo = __shfl((int)(v & 0xFFFFFFFFull), src);
  int hi = __shfl((int)(v >> 32), src);
  return ((u64)(unsigned)hi << 32) | (unsigned)lo;
}

__global__ __launch_bounds__(256) void prep_kernel(
    const float* __restrict__ x,
    const float* __restrict__ w0, const float* __restrict__ g0, const float* __restrict__ b0,
    const float* __restrict__ w1, const float* __restrict__ g1, const float* __restrict__ b1,
    const float* __restrict__ wout, const float* __restrict__ gout, const float* __restrict__ bout,
    float* __restrict__ wsf, unsigned short* __restrict__ whi, unsigned short* __restrict__ wlo,
    float4* __restrict__ xq) {
  const float rs = 1.0f / sqrtf(1.0f + 1e-5f);
  int t = blockIdx.x * 256 + threadIdx.x;
  if (t < 384) wsf[OFF_W0S + t] = w0[t] * (g0[t / 6] * rs);
  if (t < 64) {
    wsf[OFF_B0F + t] = b0[t];
    wsf[OFF_S1F + t] = g1[t] * rs;
    wsf[OFF_B1F + t] = b1[t];
  }
  if (t < 192) wsf[OFF_WOUTS + t] = wout[t] * (gout[t / 64] * rs);
  if (t < 3) wsf[OFF_BOUTF + t] = bout[t];
  if (t < BATCH * NPTS) {
    int bb = t >> 12, j = t & (NPTS - 1);
    const float* xb = x + bb * 3 * NPTS;
    float x0 = xb[j], x1 = xb[NPTS + j], x2 = xb[2 * NPTS + j];
    float xx = x0 * x0 + x1 * x1 + x2 * x2;
    xq[t] = make_float4(x0, x1, x2, xx);
  }
  // B-fragment layout for mfma_f32_16x16x32_bf16: frag ft = kk*4+nt; lane L holds
  // B[k = kk*32 + (L>>4)*8 + j][n = nt*16 + (L&15)], j packed consecutively.
  if (t < 24576) {
    int j = t & 7, L = (t >> 3) & 63, ft = t >> 9;
    int kk = ft >> 2, nt = ft & 3;
    int k = kk * 32 + ((L >> 4) << 3) + j;
    int c = k >> 6, d = k & 63;
    int o = nt * 16 + (L & 15);
    float w = w1[(o * 6 + c) * 64 + d];
    unsigned bw = __float_as_uint(w);
    unsigned hb = bw & 0xFFFF0000u;
    float r = w - __uint_as_float(hb);
    whi[t] = (unsigned short)(bw >> 16);
    wlo[t] = (unsigned short)(__float_as_uint(r) >> 16);
  }
}

// knn v2.1 (round-6 v2 + unroll 8): single-scan register top-2 cache, u64 keys,
// butterfly argmax. unroll 8 => 8 L2 loads in flight in phase A (round-6's
// unroll 4 under-covered ~200cyc L2 latency at ~5 resident waves).
__global__ __launch_bounds__(64, 4) void knn_kernel(const float4* __restrict__ xq,
                                                    unsigned short* __restrict__ idxbuf) {
  const int pt = blockIdx.x;
  const int b = pt >> 12, n = pt & (NPTS - 1);
  const int lane = threadIdx.x;
  const float4* xqb = xq + b * NPTS;
  const float4 xin = xqb[n];
  const float xi0 = xin.x, xi1 = xin.y, xi2 = xin.z;
  const float nxxi = -xin.w;

  u64 k1 = 0, k2 = 0;
  unsigned lo = 4095u - (unsigned)lane;
#pragma unroll 8
  for (int s = 0; s < 64; ++s) {
    float4 q = xqb[s * 64 + lane];
    float dot = xi0 * q.x + xi1 * q.y + xi2 * q.z;
    float pd = fmaf(2.0f, dot, nxxi) - q.w;   // bit-identical to ref expr
    u64 k = ((u64)(~__float_as_uint(pd)) << 32) | lo;
    lo -= 64u;
    bool c1 = k > k1;
    bool c2 = k > k2;
    u64 t = c1 ? k1 : k;
    k2 = c2 ? t : k2;
    k1 = c1 ? k : k1;
  }

  u64 tk = 0;
  unsigned myout = 0;
#pragma unroll 1
  for (int r = 0; r < KNN; ++r) {
    u64 bk = k1;
    for (int off = 32; off > 0; off >>= 1) {
      u64 ok = shflx64(bk, off);
      if (ok > bk) bk = ok;
    }
    unsigned bj = 4095u - (unsigned)(bk & 4095u);
    if (lane == r) myout = bj;
    bool owner = (k1 == bk);
    u64 bit = 1ull << (bj >> 6);
    if (owner) {
      tk |= bit;
      k1 = k2;
      k2 = 0;
    }
    bool need = owner && (k1 == 0);
    u64 nm = __ballot(need);
    if (nm) {
      int LN = __ffsll(nm) - 1;
      int j2 = lane * 64 + LN;
      float4 q = xqb[j2];
      float dot = xi0 * q.x + xi1 * q.y + xi2 * q.z;
      float pd = fmaf(2.0f, dot, nxxi) - q.w;
      u64 kk = ((u64)(~__float_as_uint(pd)) << 32) | (4095u - (unsigned)j2);
      u64 tkl = shflbc64(tk, LN);
      if ((tkl >> lane) & 1) kk = 0;
      u64 w1k = kk;
      for (int off = 32; off > 0; off >>= 1) {
        u64 ok = shflx64(w1k, off);
        if (ok > w1k) w1k = ok;
      }
      u64 kk2 = (kk == w1k) ? 0 : kk;
      u64 w2k = kk2;
      for (int off = 32; off > 0; off >>= 1) {
        u64 ok = shflx64(w2k, off);
        if (ok > w2k) w2k = ok;
      }
      if (lane == LN) { k1 = w1k; k2 = w2k; }
    }
  }
  if (lane < KNN) idxbuf[pt * KNN + lane] = (unsigned short)myout;
}

// mlp v4 (round-6 version, unchanged): hh-outer K-order, 40-reg h fragments,
// explicit B double-buffer, 5 M-tiles/wave.
__global__ __launch_bounds__(64, 2) void mlp_kernel(const float4* __restrict__ xq,
                                                    const float* __restrict__ wsf,
                                                    const unsigned short* __restrict__ whi,
                                                    const unsigned short* __restrict__ wlo,
                                                    const unsigned short* __restrict__ idxbuf,
                                                    float* __restrict__ out) {
  __shared__ float w0l[448];
  __shared__ float v6l[80 * 12];
  __shared__ float pmax[20 * 66];

  const int lane = threadIdx.x;
  const int quad = lane >> 4, l15 = lane & 15;
  const int pt_base = blockIdx.x * 4;

  const i32x4* whp = (const i32x4*)whi;
  const i32x4* wlp = (const i32x4*)wlo;

  i32x4 wh[4], wl[4];
#pragma unroll
  for (int nt = 0; nt < 4; ++nt) {
    wh[nt] = whp[nt * 64 + lane];
    wl[nt] = wlp[nt * 64 + lane];
  }

  for (int i = lane; i < 448; i += 64) w0l[i] = wsf[i];

#pragma unroll
  for (int rep = 0; rep < 2; ++rep) {
    int e = rep * 64 + lane;
    if (e < 80) {
      int p = e / 20, el = e - p * 20;
      int pt = pt_base + p;
      int b = pt >> 12, n = pt & (NPTS - 1);
      float4 xi = xq[b * NPTS + n];
      int jn = idxbuf[pt * KNN + el];
      float4 xj = xq[b * NPTS + jn];
      v6l[e * 12 + 0] = xj.x - xi.x;
      v6l[e * 12 + 1] = xj.y - xi.y;
      v6l[e * 12 + 2] = xj.z - xi.z;
      v6l[e * 12 + 3] = xi.x;
      v6l[e * 12 + 4] = xi.y;
      v6l[e * 12 + 5] = xi.z;
    }
  }
  __syncthreads();

  f32x4 acc[5][4];
#pragma unroll
  for (int t = 0; t < 5; ++t)
#pragma unroll
    for (int nt = 0; nt < 4; ++nt) acc[t][nt] = (f32x4){0.f, 0.f, 0.f, 0.f};

#pragma unroll 1
  for (int hh = 0; hh < 2; ++hh) {
    float v6r[5][6];
#pragma unroll
    for (int t = 0; t < 5; ++t) {
      const float* vr = v6l + (t * 16 + l15) * 12;
      f32x4 a4 = *(const f32x4*)vr;
      v6r[t][0] = a4.x; v6r[t][1] = a4.y; v6r[t][2] = a4.z; v6r[t][3] = a4.w;
      v6r[t][4] = vr[4]; v6r[t][5] = vr[5];
    }
    float hf[5][8];
#pragma unroll
    for (int j = 0; j < 8; ++j) {
      const int d = hh * 32 + quad * 8 + j;
      const float* wr = w0l + d * 6;
      float wc0 = wr[0], wc1 = wr[1], wc2 = wr[2];
      float wc3 = wr[3], wc4 = wr[4], wc5 = wr[5];
      float bb = w0l[384 + d];
#pragma unroll
      for (int t = 0; t < 5; ++t) {
        float a = bb + wc0 * v6r[t][0] + wc1 * v6r[t][1] + wc2 * v6r[t][2]
                     + wc3 * v6r[t][3] + wc4 * v6r[t][4] + wc5 * v6r[t][5];
        hf[t][j] = fmaxf(a, 0.2f * a);
      }
    }

#pragma unroll 1
    for (int cc = 0; cc < 6; ++cc) {
      const int kk = cc * 2 + hh;
      const bool hasnext = !(hh == 1 && cc == 5);
      const int kkn = (cc < 5) ? kk + 2 : 1;
      i32x4 whn[4], wln[4];
      if (hasnext) {
#pragma unroll
        for (int nt = 0; nt < 4; ++nt) {
          whn[nt] = whp[(kkn * 4 + nt) * 64 + lane];
          wln[nt] = wlp[(kkn * 4 + nt) * 64 + lane];
        }
      }
#pragma unroll
      for (int t = 0; t < 5; ++t) {
        float vc = v6l[(t * 16 + l15) * 12 + cc];
        float u0 = vc * hf[t][0], u1 = vc * hf[t][1];
        float u2 = vc * hf[t][2], u3 = vc * hf[t][3];
        float u4 = vc * hf[t][4], u5 = vc * hf[t][5];
        float u6 = vc * hf[t][6], u7 = vc * hf[t][7];
        unsigned ub0 = __float_as_uint(u0), ub1 = __float_as_uint(u1);
        unsigned ub2 = __float_as_uint(u2), ub3 = __float_as_uint(u3);
        unsigned ub4 = __float_as_uint(u4), ub5 = __float_as_uint(u5);
        unsigned ub6 = __float_as_uint(u6), ub7 = __float_as_uint(u7);
        float r0 = u0 - __uint_as_float(ub0 & 0xFFFF0000u);
        float r1 = u1 - __uint_as_float(ub1 & 0xFFFF0000u);
        float r2 = u2 - __uint_as_float(ub2 & 0xFFFF0000u);
        float r3 = u3 - __uint_as_float(ub3 & 0xFFFF0000u);
        float r4 = u4 - __uint_as_float(ub4 & 0xFFFF0000u);
        float r5 = u5 - __uint_as_float(ub5 & 0xFFFF0000u);
        float r6 = u6 - __uint_as_float(ub6 & 0xFFFF0000u);
        float r7 = u7 - __uint_as_float(ub7 & 0xFFFF0000u);
        i32x4 ah, al;
        ah.x = __builtin_amdgcn_perm(ub1, ub0, 0x07060302);
        ah.y = __builtin_amdgcn_perm(ub3, ub2, 0x07060302);
        ah.z = __builtin_amdgcn_perm(ub5, ub4, 0x07060302);
        ah.w = __builtin_amdgcn_perm(ub7, ub6, 0x07060302);
        al.x = __builtin_amdgcn_perm(__float_as_uint(r1), __float_as_uint(r0), 0x07060302);
        al.y = __builtin_amdgcn_perm(__float_as_uint(r3), __float_as_uint(r2), 0x07060302);
        al.z = __builtin_amdgcn_perm(__float_as_uint(r5), __float_as_uint(r4), 0x07060302);
        al.w = __builtin_amdgcn_perm(__float_as_uint(r7), __float_as_uint(r6), 0x07060302);
        bf16x8 ahv = __builtin_bit_cast(bf16x8, ah);
        bf16x8 alv = __builtin_bit_cast(bf16x8, al);
#pragma unroll
        for (int nt = 0; nt < 4; ++nt) {
          bf16x8 bh = __builtin_bit_cast(bf16x8, wh[nt]);
          bf16x8 bl = __builtin_bit_cast(bf16x8, wl[nt]);
          acc[t][nt] = __builtin_amdgcn_mfma_f32_16x16x32_bf16(ahv, bh, acc[t][nt], 0, 0, 0);
          acc[t][nt] = __builtin_amdgcn_mfma_f32_16x16x32_bf16(ahv, bl, acc[t][nt], 0, 0, 0);
          acc[t][nt] = __builtin_amdgcn_mfma_f32_16x16x32_bf16(alv, bh, acc[t][nt], 0, 0, 0);
        }
      }
      if (hasnext) {
#pragma unroll
        for (int nt = 0; nt < 4; ++nt) { wh[nt] = whn[nt]; wl[nt] = wln[nt]; }
      }
    }
  }
  __syncthreads();

  float s1v[4], b1v[4];
#pragma unroll
  for (int nt = 0; nt < 4; ++nt) {
    s1v[nt] = wsf[OFF_S1F + nt * 16 + l15];
    b1v[nt] = wsf[OFF_B1F + nt * 16 + l15];
  }
#pragma unroll
  for (int t = 0; t < 5; ++t) {
#pragma unroll
    for (int nt = 0; nt < 4; ++nt) {
      f32x4 a = acc[t][nt];
      float z0 = a.x * s1v[nt] + b1v[nt]; z0 = fmaxf(z0, 0.2f * z0);
      float z1 = a.y * s1v[nt] + b1v[nt]; z1 = fmaxf(z1, 0.2f * z1);
      float z2 = a.z * s1v[nt] + b1v[nt]; z2 = fmaxf(z2, 0.2f * z2);
      float z3 = a.w * s1v[nt] + b1v[nt]; z3 = fmaxf(z3, 0.2f * z3);
      float m4 = fmaxf(fmaxf(z0, z1), fmaxf(z2, z3));
      pmax[(t * 4 + quad) * 66 + nt * 16 + l15] = m4;
    }
  }
  __syncthreads();

  float woutr[3];
#pragma unroll
  for (int m = 0; m < 3; ++m) woutr[m] = wsf[OFF_WOUTS + m * 64 + lane];
#pragma unroll
  for (int p = 0; p < 4; ++p) {
    float x1 = pmax[(p * 5 + 0) * 66 + lane];
    x1 = fmaxf(x1, pmax[(p * 5 + 1) * 66 + lane]);
    x1 = fmaxf(x1, pmax[(p * 5 + 2) * 66 + lane]);
    x1 = fmaxf(x1, pmax[(p * 5 + 3) * 66 + lane]);
    x1 = fmaxf(x1, pmax[(p * 5 + 4) * 66 + lane]);
    int pt = pt_base + p;
    int b = pt >> 12, n = pt & (NPTS - 1);
#pragma unroll
    for (int m = 0; m < 3; ++m) {
      float part = woutr[m] * x1;
      for (int off = 32; off > 0; off >>= 1) part += __shfl_xor(part, off);
      if (lane == 0) {
        float ov = part + wsf[OFF_BOUTF + m];
        out[(b * 3 + m) * NPTS + n] = fmaxf(ov, 0.2f * ov);
      }
    }
  }
}

extern "C" void kernel_launch(void* const* d_in, const int* in_sizes, int n_in,
                              void* d_out, int out_size, void* d_ws, size_t ws_size,
                              hipStream_t stream) {
  const float* x    = (const float*)d_in[0];
  const float* w0   = (const float*)d_in[1];
  const float* g0   = (const float*)d_in[2];
  const float* b0   = (const float*)d_in[3];
  const float* w1   = (const float*)d_in[4];
  const float* g1   = (const float*)d_in[5];
  const float* b1   = (const float*)d_in[6];
  const float* wout = (const float*)d_in[7];
  const float* gout = (const float*)d_in[8];
  const float* bout = (const float*)d_in[9];
  float* wsf = (float*)d_ws;
  unsigned short* whi = (unsigned short*)((char*)d_ws + OFF_WHI_BYTES);
  unsigned short* wlo = (unsigned short*)((char*)d_ws + OFF_WLO_BYTES);
  unsigned short* idxbuf = (unsigned short*)((char*)d_ws + OFF_IDX_BYTES);
  float4* xq = (float4*)((char*)d_ws + OFF_XQ_BYTES);
  float* out = (float*)d_out;

  prep_kernel<<<96, 256, 0, stream>>>(x, w0, g0, b0, w1, g1, b1, wout, gout, bout,
                                      wsf, whi, wlo, xq);
  knn_kernel<<<BATCH * NPTS, 64, 0, stream>>>(xq, idxbuf);
  mlp_kernel<<<BATCH * NPTS / 4, 64, 0, stream>>>(xq, wsf, whi, wlo, idxbuf, out);
}